// Round 1
// baseline (509.072 us; speedup 1.0000x reference)
//
#include <hip/hip_runtime.h>
#include <hip/hip_bf16.h>

#define TOK 4096
#define DIM 1024
#define HID 2048
#define LN10K 9.210340371976184f

typedef __bf16 bh;
typedef __bf16 v8bf __attribute__((ext_vector_type(8)));
typedef float v4f __attribute__((ext_vector_type(4)));

// ---------------- prep: cast X -> feat left half, colsum(E) ----------------
__global__ __launch_bounds__(256) void prep_x_colsum(const float* __restrict__ X,
                                                     bh* __restrict__ featb,
                                                     float* __restrict__ S) {
  int c = blockIdx.x * 256 + threadIdx.x;   // 0..DIM-1
  int r0 = blockIdx.y * 128;
  float inv_denom = expf(-(float)(c & ~1) * (LN10K / (float)DIM));
  bool odd = c & 1;
  float sum = 0.f;
  for (int r = r0; r < r0 + 128; ++r) {
    float x = X[(size_t)r * DIM + c];
    featb[(size_t)r * (2 * DIM) + c] = (bh)x;
    float ang = (float)r * inv_denom;
    float pe = odd ? cosf(ang) : sinf(ang);
    sum += pe * x;
  }
  atomicAdd(&S[c], sum);
}

// ---------------- prep: loo -> feat right half ----------------
__global__ __launch_bounds__(256) void prep_loo(const float* __restrict__ X,
                                                const float* __restrict__ S,
                                                bh* __restrict__ featb) {
  size_t idx = (size_t)blockIdx.x * 256 + threadIdx.x;  // over TOK*DIM
  int r = (int)(idx >> 10);
  int c = (int)(idx & 1023);
  float inv_denom = expf(-(float)(c & ~1) * (LN10K / (float)DIM));
  float ang = (float)r * inv_denom;
  float pe = (c & 1) ? cosf(ang) : sinf(ang);
  float e = pe * X[idx];
  float loo = (S[c] - e) * (1.0f / (float)(TOK - 1));
  featb[(size_t)r * (2 * DIM) + DIM + c] = (bh)loo;
}

// ---------------- transpose + cast fp32 (R x Ncol) -> bf16 (Ncol x R) ----------------
__global__ __launch_bounds__(256) void transpose_cast(const float* __restrict__ in,
                                                      bh* __restrict__ out,
                                                      int R, int Ncol) {
  __shared__ float tile[32][33];
  int nb = blockIdx.x * 32, rb = blockIdx.y * 32;
  int tx = threadIdx.x, ty = threadIdx.y;  // block (32,8)
#pragma unroll
  for (int j = 0; j < 32; j += 8)
    tile[ty + j][tx] = in[(size_t)(rb + ty + j) * Ncol + nb + tx];
  __syncthreads();
#pragma unroll
  for (int j = 0; j < 32; j += 8)
    out[(size_t)(nb + ty + j) * R + rb + tx] = (bh)tile[tx][ty + j];
}

// ---------------- GEMM: C = act(A @ BT^T + bias) ----------------
// A: M x K row-major bf16 (lda). BT: N x K row-major bf16 (ldbt) (i.e. B^T).
// 128x128 block tile, 4 waves, each wave 64x64 via 4x4 MFMA 16x16x32 tiles.
template <bool RELU, bool TROUT, typename OutT>
__global__ __launch_bounds__(256) void gemm_bt(const bh* __restrict__ A,
                                               const bh* __restrict__ BT,
                                               const float* __restrict__ bias,
                                               OutT* __restrict__ C,
                                               int M, int N, int K,
                                               int lda, int ldbt, int ldc) {
  (void)M; (void)N;
  __shared__ bh As[128 * 32];
  __shared__ bh Bs[128 * 32];
  const int t = threadIdx.x;
  const int bm = blockIdx.y * 128, bn = blockIdx.x * 128;

  // staging map: thread t covers row tr (+64), k-chunk tk; LDS offset = t*8 elems (linear)
  const int tr = t >> 2, tk = (t & 3) * 8;
  const bh* ga0 = A + (size_t)(bm + tr) * lda + tk;
  const bh* ga1 = ga0 + (size_t)64 * lda;
  const bh* gb0 = BT + (size_t)(bn + tr) * ldbt + tk;
  const bh* gb1 = gb0 + (size_t)64 * ldbt;
  bh* sA0 = As + t * 8; bh* sA1 = As + 2048 + t * 8;
  bh* sB0 = Bs + t * 8; bh* sB1 = Bs + 2048 + t * 8;

  const int lane = t & 63, wave = t >> 6;
  const int wm = (wave >> 1) * 64, wn = (wave & 1) * 64;
  const int lc = lane & 15, q = lane >> 4;
  // A-operand: A[m = lane&15][k = q*8 + j]; B-operand: B[k = q*8 + j][n = lane&15]
  const bh* rA = As + (wm + lc) * 32 + q * 8;
  const bh* rB = Bs + (wn + lc) * 32 + q * 8;

  v4f acc[4][4] = {};
  for (int k0 = 0; k0 < K; k0 += 32) {
    uint4 va0 = *(const uint4*)(ga0 + k0);
    uint4 va1 = *(const uint4*)(ga1 + k0);
    uint4 vb0 = *(const uint4*)(gb0 + k0);
    uint4 vb1 = *(const uint4*)(gb1 + k0);
    *(uint4*)sA0 = va0; *(uint4*)sA1 = va1;
    *(uint4*)sB0 = vb0; *(uint4*)sB1 = vb1;
    __syncthreads();
    v8bf af[4], bfr[4];
#pragma unroll
    for (int i = 0; i < 4; ++i) {
      af[i]  = *(const v8bf*)(rA + i * (16 * 32));
      bfr[i] = *(const v8bf*)(rB + i * (16 * 32));
    }
#pragma unroll
    for (int mt = 0; mt < 4; ++mt)
#pragma unroll
      for (int nt = 0; nt < 4; ++nt)
        acc[mt][nt] = __builtin_amdgcn_mfma_f32_16x16x32_bf16(af[mt], bfr[nt], acc[mt][nt], 0, 0, 0);
    __syncthreads();
  }

  // C/D layout: col = lane&15, row = q*4 + r   (m89-verified)
  const int r4 = q * 4;
#pragma unroll
  for (int mt = 0; mt < 4; ++mt) {
    int row0 = bm + wm + mt * 16 + r4;
#pragma unroll
    for (int nt = 0; nt < 4; ++nt) {
      int col = bn + wn + nt * 16 + lc;
      float bb = bias ? bias[col] : 0.0f;
#pragma unroll
      for (int r = 0; r < 4; ++r) {
        float val = acc[mt][nt][r] + bb;
        if (RELU) val = fmaxf(val, 0.0f);
        if (TROUT) C[(size_t)col * ldc + (row0 + r)] = (OutT)val;
        else       C[(size_t)(row0 + r) * ldc + col] = (OutT)val;
      }
    }
  }
}

// ---------------- row softmax in place on bf16 (TOK cols) ----------------
__global__ __launch_bounds__(256) void softmax_inplace(bh* __restrict__ P) {
  int row = blockIdx.x;
  bh* p = P + (size_t)row * TOK;
  int t = threadIdx.x;
  v8bf c0 = *(v8bf*)(p + t * 16);
  v8bf c1 = *(v8bf*)(p + t * 16 + 8);
  float v[16];
#pragma unroll
  for (int i = 0; i < 8; ++i) { v[i] = (float)c0[i]; v[8 + i] = (float)c1[i]; }
  float m = v[0];
#pragma unroll
  for (int i = 1; i < 16; ++i) m = fmaxf(m, v[i]);
#pragma unroll
  for (int off = 32; off > 0; off >>= 1) m = fmaxf(m, __shfl_xor(m, off));
  __shared__ float redm[4], reds[4];
  int lane = t & 63, w = t >> 6;
  if (lane == 0) redm[w] = m;
  __syncthreads();
  m = fmaxf(fmaxf(redm[0], redm[1]), fmaxf(redm[2], redm[3]));
  float s = 0.f;
#pragma unroll
  for (int i = 0; i < 16; ++i) { v[i] = __expf(v[i] - m); s += v[i]; }
#pragma unroll
  for (int off = 32; off > 0; off >>= 1) s += __shfl_xor(s, off);
  if (lane == 0) reds[w] = s;
  __syncthreads();
  s = reds[0] + reds[1] + reds[2] + reds[3];
  float inv = 1.0f / s;
#pragma unroll
  for (int i = 0; i < 8; ++i) { c0[i] = (bh)(v[i] * inv); c1[i] = (bh)(v[8 + i] * inv); }
  *(v8bf*)(p + t * 16) = c0;
  *(v8bf*)(p + t * 16 + 8) = c1;
}

extern "C" void kernel_launch(void* const* d_in, const int* in_sizes, int n_in,
                              void* d_out, int out_size, void* d_ws, size_t ws_size,
                              hipStream_t stream) {
  (void)in_sizes; (void)n_in; (void)out_size; (void)ws_size;
  const float* X  = (const float*)d_in[0];
  // d_in[1] = mask, unused by the module
  const float* Wv = (const float*)d_in[2];
  const float* bv = (const float*)d_in[3];
  const float* W1 = (const float*)d_in[4];
  const float* b1 = (const float*)d_in[5];
  const float* W2 = (const float*)d_in[6];
  const float* b2 = (const float*)d_in[7];
  float* out = (float*)d_out;

  char* ws = (char*)d_ws;
  bh* featb = (bh*)(ws);                       // 4096 x 2048 bf16 : 16 MiB
  bh* WvT   = (bh*)(ws + (16u << 20));         // 1024 x 1024      :  2 MiB
  bh* W1T   = (bh*)(ws + (18u << 20));         // 2048 x 2048      :  8 MiB
  bh* W2T   = (bh*)(ws + (26u << 20));         // 4096 x 2048      : 16 MiB
  bh* Vt    = (bh*)(ws + (42u << 20));         // 1024 x 4096      :  8 MiB
  bh* hid   = (bh*)(ws + (50u << 20));         // 4096 x 2048      : 16 MiB
  bh* scr   = (bh*)(ws + (66u << 20));         // 4096 x 4096      : 32 MiB
  float* S  = (float*)(ws + (98u << 20));      // 1024 fp32

  hipMemsetAsync(S, 0, DIM * sizeof(float), stream);
  prep_x_colsum<<<dim3(DIM / 256, 32), 256, 0, stream>>>(X, featb, S);
  prep_loo<<<dim3((TOK * DIM) / 256), 256, 0, stream>>>(X, S, featb);
  transpose_cast<<<dim3(DIM / 32, DIM / 32), dim3(32, 8), 0, stream>>>(Wv, WvT, DIM, DIM);
  transpose_cast<<<dim3(HID / 32, (2 * DIM) / 32), dim3(32, 8), 0, stream>>>(W1, W1T, 2 * DIM, HID);
  transpose_cast<<<dim3(TOK / 32, HID / 32), dim3(32, 8), 0, stream>>>(W2, W2T, HID, TOK);

  // V^T = (feat_left @ Wv + bv)^T  -> Vt (1024 x 4096, ld 4096)
  gemm_bt<false, true, bh><<<dim3(DIM / 128, TOK / 128), 256, 0, stream>>>(
      featb, WvT, bv, Vt, TOK, DIM, DIM, 2 * DIM, DIM, TOK);
  // hid = relu(feat @ W1 + b1)
  gemm_bt<true, false, bh><<<dim3(HID / 128, TOK / 128), 256, 0, stream>>>(
      featb, W1T, b1, hid, TOK, HID, 2 * DIM, 2 * DIM, 2 * DIM, HID);
  // scr = hid @ W2 + b2
  gemm_bt<false, false, bh><<<dim3(TOK / 128, TOK / 128), 256, 0, stream>>>(
      hid, W2T, b2, scr, TOK, TOK, HID, HID, HID, TOK);
  softmax_inplace<<<dim3(TOK), 256, 0, stream>>>(scr);
  // out = softmax(scr) @ V  (A = weights row-major, BT = Vt) -> fp32 d_out
  gemm_bt<false, false, float><<<dim3(DIM / 128, TOK / 128), 256, 0, stream>>>(
      scr, Vt, nullptr, out, TOK, DIM, TOK, TOK, TOK, DIM);
}

// Round 2
// 465.111 us; speedup vs baseline: 1.0945x; 1.0945x over previous
//
#include <hip/hip_runtime.h>
#include <hip/hip_bf16.h>

#define TOK 4096
#define DIM 1024
#define HID 2048
#define LN10K 9.210340371976184f

typedef __bf16 bh;
typedef __bf16 v8bf __attribute__((ext_vector_type(8)));
typedef float v4f __attribute__((ext_vector_type(4)));

typedef const __attribute__((address_space(1))) void* gvp;
typedef __attribute__((address_space(3))) void* svp;

__device__ __forceinline__ void gl_lds16(const bh* g, bh* s) {
  __builtin_amdgcn_global_load_lds((gvp)g, (svp)s, 16, 0, 0);
}

// ---------------- prep: cast X -> feat left half, colsum(E) ----------------
__global__ __launch_bounds__(256) void prep_x_colsum(const float* __restrict__ X,
                                                     bh* __restrict__ featb,
                                                     float* __restrict__ S) {
  int c = blockIdx.x * 256 + threadIdx.x;   // 0..DIM-1
  int r0 = blockIdx.y * 128;
  float inv_denom = expf(-(float)(c & ~1) * (LN10K / (float)DIM));
  bool odd = c & 1;
  float sum = 0.f;
  for (int r = r0; r < r0 + 128; ++r) {
    float x = X[(size_t)r * DIM + c];
    featb[(size_t)r * (2 * DIM) + c] = (bh)x;
    float ang = (float)r * inv_denom;
    float pe = odd ? cosf(ang) : sinf(ang);
    sum += pe * x;
  }
  atomicAdd(&S[c], sum);
}

// ---------------- prep: loo -> feat right half ----------------
__global__ __launch_bounds__(256) void prep_loo(const float* __restrict__ X,
                                                const float* __restrict__ S,
                                                bh* __restrict__ featb) {
  size_t idx = (size_t)blockIdx.x * 256 + threadIdx.x;  // over TOK*DIM
  int r = (int)(idx >> 10);
  int c = (int)(idx & 1023);
  float inv_denom = expf(-(float)(c & ~1) * (LN10K / (float)DIM));
  float ang = (float)r * inv_denom;
  float pe = (c & 1) ? cosf(ang) : sinf(ang);
  float e = pe * X[idx];
  float loo = (S[c] - e) * (1.0f / (float)(TOK - 1));
  featb[(size_t)r * (2 * DIM) + DIM + c] = (bh)loo;
}

// ---------------- transpose + cast fp32 (R x Ncol) -> bf16 (Ncol x R) ----------------
__global__ __launch_bounds__(256) void transpose_cast(const float* __restrict__ in,
                                                      bh* __restrict__ out,
                                                      int R, int Ncol) {
  __shared__ float tile[32][33];
  int nb = blockIdx.x * 32, rb = blockIdx.y * 32;
  int tx = threadIdx.x, ty = threadIdx.y;  // block (32,8)
#pragma unroll
  for (int j = 0; j < 32; j += 8)
    tile[ty + j][tx] = in[(size_t)(rb + ty + j) * Ncol + nb + tx];
  __syncthreads();
#pragma unroll
  for (int j = 0; j < 32; j += 8)
    out[(size_t)(nb + ty + j) * R + rb + tx] = (bh)tile[tx][ty + j];
}

// ---------------- GEMM: C = act(A @ BT^T + bias) ----------------
// A: M x K row-major bf16 (lda). BT: N x K row-major bf16 (ldbt) (i.e. B^T).
// Block tile 128 x BN, 4 waves (wave tile 64 x BN/2), 16x16x32 bf16 MFMA.
// Staging: global_load_lds width=16 (wave-uniform base + lane*16 — lane-linear
// LDS layout required). K-chunk XOR swizzle (chunk ^= (row>>1)&3, 16B grain)
// applied on the GLOBAL side so the lane-linear LDS write stays legal while
// read-side ds_read_b128 bank aliasing drops to 2-way (free per m136).
template <int BN, bool RELU, bool TROUT, typename OutT>
__global__ __launch_bounds__(256) void gemm_bt(const bh* __restrict__ A,
                                               const bh* __restrict__ BT,
                                               const float* __restrict__ bias,
                                               OutT* __restrict__ C,
                                               int K, int lda, int ldbt, int ldc) {
  constexpr int WN = BN / 2;       // wave tile N
  constexpr int NT = WN / 16;      // 4 (BN=128) or 2 (BN=64)
  __shared__ bh As[128 * 32];
  __shared__ bh Bs[BN * 32];
  const int t = threadIdx.x;
  const int bm = blockIdx.y * 128, bn = blockIdx.x * BN;

  // staging map: thread t covers row tr (+64), stored-chunk t&3; LDS dst = t*16B
  const int tr = t >> 2;
  const int sw = (tr >> 1) & 3;                // same for tr and tr+64
  const int tkA = ((t & 3) ^ sw) * 8;          // logical k-chunk (swizzled)
  const bh* ga0 = A + (size_t)(bm + tr) * lda + tkA;
  const bh* ga1 = ga0 + (size_t)64 * lda;
  const bh* gb0 = BT + (size_t)(bn + tr) * ldbt + tkA;
  const bh* gb1 = gb0 + (size_t)64 * ldbt;     // only used when BN==128
  bh* sA0 = As + t * 8; bh* sA1 = As + 2048 + t * 8;
  bh* sB0 = Bs + t * 8; bh* sB1 = Bs + 2048 + t * 8;

  const int lane = t & 63, wave = t >> 6;
  const int wm = (wave >> 1) * 64, wn = (wave & 1) * WN;
  const int lc = lane & 15, q = lane >> 4;
  // A-operand: A[m = lc][k = q*8 + j]; B-operand: B[k = q*8 + j][n = lc]
  const int rowA = wm + lc, rowB = wn + lc;
  const bh* rA = As + rowA * 32 + ((q ^ ((rowA >> 1) & 3)) * 8);
  const bh* rB = Bs + rowB * 32 + ((q ^ ((rowB >> 1) & 3)) * 8);

  v4f acc[4][NT] = {};
  for (int k0 = 0; k0 < K; k0 += 32) {
    gl_lds16(ga0 + k0, sA0);
    gl_lds16(ga1 + k0, sA1);
    gl_lds16(gb0 + k0, sB0);
    if (BN == 128) gl_lds16(gb1 + k0, sB1);
    __syncthreads();   // vmcnt(0) drain + barrier
    v8bf af[4], bfr[NT];
#pragma unroll
    for (int i = 0; i < 4; ++i) af[i] = *(const v8bf*)(rA + i * (16 * 32));
#pragma unroll
    for (int i = 0; i < NT; ++i) bfr[i] = *(const v8bf*)(rB + i * (16 * 32));
#pragma unroll
    for (int mt = 0; mt < 4; ++mt)
#pragma unroll
      for (int nt = 0; nt < NT; ++nt)
        acc[mt][nt] = __builtin_amdgcn_mfma_f32_16x16x32_bf16(af[mt], bfr[nt], acc[mt][nt], 0, 0, 0);
    __syncthreads();   // readers done before next overwrite
  }

  // C/D layout: col = lane&15, row = q*4 + r   (m89-verified)
  const int r4 = q * 4;
#pragma unroll
  for (int mt = 0; mt < 4; ++mt) {
    int row0 = bm + wm + mt * 16 + r4;
#pragma unroll
    for (int nt = 0; nt < NT; ++nt) {
      int col = bn + wn + nt * 16 + lc;
      float bb = bias ? bias[col] : 0.0f;
#pragma unroll
      for (int r = 0; r < 4; ++r) {
        float val = acc[mt][nt][r] + bb;
        if (RELU) val = fmaxf(val, 0.0f);
        if (TROUT) C[(size_t)col * ldc + (row0 + r)] = (OutT)val;
        else       C[(size_t)(row0 + r) * ldc + col] = (OutT)val;
      }
    }
  }
}

// ---------------- row softmax in place on bf16 (TOK cols) ----------------
__global__ __launch_bounds__(256) void softmax_inplace(bh* __restrict__ P) {
  int row = blockIdx.x;
  bh* p = P + (size_t)row * TOK;
  int t = threadIdx.x;
  v8bf c0 = *(v8bf*)(p + t * 16);
  v8bf c1 = *(v8bf*)(p + t * 16 + 8);
  float v[16];
#pragma unroll
  for (int i = 0; i < 8; ++i) { v[i] = (float)c0[i]; v[8 + i] = (float)c1[i]; }
  float m = v[0];
#pragma unroll
  for (int i = 1; i < 16; ++i) m = fmaxf(m, v[i]);
#pragma unroll
  for (int off = 32; off > 0; off >>= 1) m = fmaxf(m, __shfl_xor(m, off));
  __shared__ float redm[4], reds[4];
  int lane = t & 63, w = t >> 6;
  if (lane == 0) redm[w] = m;
  __syncthreads();
  m = fmaxf(fmaxf(redm[0], redm[1]), fmaxf(redm[2], redm[3]));
  float s = 0.f;
#pragma unroll
  for (int i = 0; i < 16; ++i) { v[i] = __expf(v[i] - m); s += v[i]; }
#pragma unroll
  for (int off = 32; off > 0; off >>= 1) s += __shfl_xor(s, off);
  if (lane == 0) reds[w] = s;
  __syncthreads();
  s = reds[0] + reds[1] + reds[2] + reds[3];
  float inv = 1.0f / s;
#pragma unroll
  for (int i = 0; i < 8; ++i) { c0[i] = (bh)(v[i] * inv); c1[i] = (bh)(v[8 + i] * inv); }
  *(v8bf*)(p + t * 16) = c0;
  *(v8bf*)(p + t * 16 + 8) = c1;
}

extern "C" void kernel_launch(void* const* d_in, const int* in_sizes, int n_in,
                              void* d_out, int out_size, void* d_ws, size_t ws_size,
                              hipStream_t stream) {
  (void)in_sizes; (void)n_in; (void)out_size; (void)ws_size;
  const float* X  = (const float*)d_in[0];
  // d_in[1] = mask, unused by the module
  const float* Wv = (const float*)d_in[2];
  const float* bv = (const float*)d_in[3];
  const float* W1 = (const float*)d_in[4];
  const float* b1 = (const float*)d_in[5];
  const float* W2 = (const float*)d_in[6];
  const float* b2 = (const float*)d_in[7];
  float* out = (float*)d_out;

  char* ws = (char*)d_ws;
  bh* featb = (bh*)(ws);                       // 4096 x 2048 bf16 : 16 MiB
  bh* WvT   = (bh*)(ws + (16u << 20));         // 1024 x 1024      :  2 MiB
  bh* W1T   = (bh*)(ws + (18u << 20));         // 2048 x 2048      :  8 MiB
  bh* W2T   = (bh*)(ws + (26u << 20));         // 4096 x 2048      : 16 MiB
  bh* Vt    = (bh*)(ws + (42u << 20));         // 1024 x 4096      :  8 MiB
  bh* hid   = (bh*)(ws + (50u << 20));         // 4096 x 2048      : 16 MiB
  bh* scr   = (bh*)(ws + (66u << 20));         // 4096 x 4096      : 32 MiB
  float* S  = (float*)(ws + (98u << 20));      // 1024 fp32

  hipMemsetAsync(S, 0, DIM * sizeof(float), stream);
  prep_x_colsum<<<dim3(DIM / 256, 32), 256, 0, stream>>>(X, featb, S);
  prep_loo<<<dim3((TOK * DIM) / 256), 256, 0, stream>>>(X, S, featb);
  transpose_cast<<<dim3(DIM / 32, DIM / 32), dim3(32, 8), 0, stream>>>(Wv, WvT, DIM, DIM);
  transpose_cast<<<dim3(HID / 32, (2 * DIM) / 32), dim3(32, 8), 0, stream>>>(W1, W1T, 2 * DIM, HID);
  transpose_cast<<<dim3(TOK / 32, HID / 32), dim3(32, 8), 0, stream>>>(W2, W2T, HID, TOK);

  // V^T = (feat_left @ Wv + bv)^T  -> Vt (1024 x 4096, ld 4096); BN=64 for occupancy
  gemm_bt<64, false, true, bh><<<dim3(DIM / 64, TOK / 128), 256, 0, stream>>>(
      featb, WvT, bv, Vt, DIM, 2 * DIM, DIM, TOK);
  // hid = relu(feat @ W1 + b1)
  gemm_bt<128, true, false, bh><<<dim3(HID / 128, TOK / 128), 256, 0, stream>>>(
      featb, W1T, b1, hid, 2 * DIM, 2 * DIM, 2 * DIM, HID);
  // scr = hid @ W2 + b2
  gemm_bt<128, false, false, bh><<<dim3(TOK / 128, TOK / 128), 256, 0, stream>>>(
      hid, W2T, b2, scr, HID, HID, HID, TOK);
  softmax_inplace<<<dim3(TOK), 256, 0, stream>>>(scr);
  // out = softmax(scr) @ V  (A = weights row-major, BT = Vt) -> fp32 d_out; BN=64
  gemm_bt<64, false, false, float><<<dim3(DIM / 64, TOK / 128), 256, 0, stream>>>(
      scr, Vt, nullptr, out, TOK, TOK, TOK, DIM);
}

// Round 3
// 425.021 us; speedup vs baseline: 1.1978x; 1.0943x over previous
//
#include <hip/hip_runtime.h>
#include <hip/hip_bf16.h>

#define TOK 4096
#define DIM 1024
#define HID 2048
#define LN10K 9.210340371976184f

typedef __bf16 bh;
typedef __bf16 v8bf __attribute__((ext_vector_type(8)));
typedef float v4f __attribute__((ext_vector_type(4)));

typedef const __attribute__((address_space(1))) void* gvp;
typedef __attribute__((address_space(3))) void* svp;

__device__ __forceinline__ void gl_lds16(const bh* g, bh* s) {
  __builtin_amdgcn_global_load_lds((gvp)g, (svp)s, 16, 0, 0);
}

// ---------------- prep: cast X -> feat left half, colsum(E) ----------------
__global__ __launch_bounds__(256) void prep_x_colsum(const float* __restrict__ X,
                                                     bh* __restrict__ featb,
                                                     float* __restrict__ S) {
  int c = blockIdx.x * 256 + threadIdx.x;   // 0..DIM-1
  int r0 = blockIdx.y * 128;
  float inv_denom = expf(-(float)(c & ~1) * (LN10K / (float)DIM));
  bool odd = c & 1;
  float sum = 0.f;
  for (int r = r0; r < r0 + 128; ++r) {
    float x = X[(size_t)r * DIM + c];
    featb[(size_t)r * (2 * DIM) + c] = (bh)x;
    float ang = (float)r * inv_denom;
    float pe = odd ? cosf(ang) : sinf(ang);
    sum += pe * x;
  }
  atomicAdd(&S[c], sum);
}

// ---------------- prep: loo -> feat right half ----------------
__global__ __launch_bounds__(256) void prep_loo(const float* __restrict__ X,
                                                const float* __restrict__ S,
                                                bh* __restrict__ featb) {
  size_t idx = (size_t)blockIdx.x * 256 + threadIdx.x;  // over TOK*DIM
  int r = (int)(idx >> 10);
  int c = (int)(idx & 1023);
  float inv_denom = expf(-(float)(c & ~1) * (LN10K / (float)DIM));
  float ang = (float)r * inv_denom;
  float pe = (c & 1) ? cosf(ang) : sinf(ang);
  float e = pe * X[idx];
  float loo = (S[c] - e) * (1.0f / (float)(TOK - 1));
  featb[(size_t)r * (2 * DIM) + DIM + c] = (bh)loo;
}

// ---------------- fused transpose+cast of all 3 weights (1 dispatch) -------
__global__ __launch_bounds__(256) void transpose_all(const float* __restrict__ Wv,
                                                     const float* __restrict__ W1,
                                                     const float* __restrict__ W2,
                                                     bh* __restrict__ WvT,
                                                     bh* __restrict__ W1T,
                                                     bh* __restrict__ W2T) {
  __shared__ float tile[32][33];
  int bid = blockIdx.x;
  const float* in; bh* out; int Ncol, R, bx, by;
  if (bid < 1024)      { in = Wv; out = WvT; Ncol = DIM; R = DIM;
                         bx = bid & 31; by = bid >> 5; }
  else if (bid < 5120) { int b = bid - 1024; in = W1; out = W1T; Ncol = HID; R = 2 * DIM;
                         bx = b & 63; by = b >> 6; }
  else                 { int b = bid - 5120; in = W2; out = W2T; Ncol = TOK; R = HID;
                         bx = b & 127; by = b >> 7; }
  int nb = bx * 32, rb = by * 32;
  int tx = threadIdx.x, ty = threadIdx.y;  // block (32,8)
#pragma unroll
  for (int j = 0; j < 32; j += 8)
    tile[ty + j][tx] = in[(size_t)(rb + ty + j) * Ncol + nb + tx];
  __syncthreads();
#pragma unroll
  for (int j = 0; j < 32; j += 8)
    out[(size_t)(nb + ty + j) * R + rb + tx] = (bh)tile[tx][ty + j];
}

// ---------------- GEMM: C = act(A @ BT^T + bias) ----------------
// A: M x K row-major bf16 (lda). BT: N x K row-major bf16 (B^T).
// 128-thread blocks (2 waves). Block tile 128 x BN, BK=64.
// Wave tile 64 x BN: wave w owns rows w*64..w*64+63, ALL BN cols.
//   -> per block-iter LDS reads: As 1x + Bs 2x (ratio vs MFMA ~0.91 at BN=128,
//      vs 1.24 for the old 2x2 64x64 arrangement).
// Staging: global_load_lds width=16, lane-linear LDS (wave-uniform base+lane*16).
// Swizzle: row r stores logical 16B-chunk c at position c ^ (r&7); since
// 16 | row-group strides, staging uses c = sp ^ (sr&7) (j-independent) and
// readers use offset ((h*4+q) ^ (lc&7)) — max 2-way bank aliasing (free, m136).
template <int BN, bool RELU, bool TROUT, typename OutT>
__global__ __launch_bounds__(128, 2) void gemm_bt(const bh* __restrict__ A,
                                                  const bh* __restrict__ BT,
                                                  const float* __restrict__ bias,
                                                  OutT* __restrict__ C,
                                                  int K, int lda, int ldbt, int ldc) {
  constexpr int NT = BN / 16;          // 8 (BN=128) or 4 (BN=64)
  __shared__ bh As[128 * 64];          // 16 KB
  __shared__ bh Bs[BN * 64];           // 16 or 8 KB
  const int t = threadIdx.x;
  const int bm = blockIdx.y * 128, bn = blockIdx.x * BN;

  const int sr = t >> 3, sp = t & 7;   // staging: row-in-group, chunk position
  const int c8 = (sp ^ (sr & 7)) * 8;  // logical k-offset (elems) for this thread
  const bh* gA = A + (size_t)(bm + sr) * lda + c8;
  const bh* gB = BT + (size_t)(bn + sr) * ldbt + c8;
  bh* sA = As + t * 8;
  bh* sB = Bs + t * 8;

  const int lane = t & 63, w = t >> 6;
  const int lc = lane & 15, q = lane >> 4;

  v4f acc[4][NT] = {};
  for (int k0 = 0; k0 < K; k0 += 64) {
#pragma unroll
    for (int j = 0; j < 8; ++j)
      gl_lds16(gA + k0 + j * 16 * lda, sA + j * 1024);
#pragma unroll
    for (int j = 0; j < NT; ++j)
      gl_lds16(gB + k0 + j * 16 * ldbt, sB + j * 1024);
    __syncthreads();   // drains vmcnt(0) + barrier
#pragma unroll
    for (int h = 0; h < 2; ++h) {
      const int off = ((h * 4 + q) ^ (lc & 7)) * 8;
      v8bf af[4], bfr[NT];
#pragma unroll
      for (int mt = 0; mt < 4; ++mt)
        af[mt] = *(const v8bf*)(As + (w * 64 + mt * 16 + lc) * 64 + off);
#pragma unroll
      for (int nt = 0; nt < NT; ++nt)
        bfr[nt] = *(const v8bf*)(Bs + (nt * 16 + lc) * 64 + off);
#pragma unroll
      for (int mt = 0; mt < 4; ++mt)
#pragma unroll
        for (int nt = 0; nt < NT; ++nt)
          acc[mt][nt] = __builtin_amdgcn_mfma_f32_16x16x32_bf16(af[mt], bfr[nt], acc[mt][nt], 0, 0, 0);
    }
    __syncthreads();
  }

  // C/D layout: col = lane&15, row = q*4 + r   (m89-verified)
  const int r4 = q * 4;
#pragma unroll
  for (int mt = 0; mt < 4; ++mt) {
    int row0 = bm + w * 64 + mt * 16 + r4;
#pragma unroll
    for (int nt = 0; nt < NT; ++nt) {
      int col = bn + nt * 16 + lc;
      float bb = bias ? bias[col] : 0.0f;
#pragma unroll
      for (int r = 0; r < 4; ++r) {
        float val = acc[mt][nt][r] + bb;
        if (RELU) val = fmaxf(val, 0.0f);
        if (TROUT) C[(size_t)col * ldc + (row0 + r)] = (OutT)val;
        else       C[(size_t)(row0 + r) * ldc + col] = (OutT)val;
      }
    }
  }
}

// ---------------- row softmax in place on bf16 (TOK cols) ----------------
__global__ __launch_bounds__(256) void softmax_inplace(bh* __restrict__ P) {
  int row = blockIdx.x;
  bh* p = P + (size_t)row * TOK;
  int t = threadIdx.x;
  v8bf c0 = *(v8bf*)(p + t * 16);
  v8bf c1 = *(v8bf*)(p + t * 16 + 8);
  float v[16];
#pragma unroll
  for (int i = 0; i < 8; ++i) { v[i] = (float)c0[i]; v[8 + i] = (float)c1[i]; }
  float m = v[0];
#pragma unroll
  for (int i = 1; i < 16; ++i) m = fmaxf(m, v[i]);
#pragma unroll
  for (int off = 32; off > 0; off >>= 1) m = fmaxf(m, __shfl_xor(m, off));
  __shared__ float redm[4], reds[4];
  int lane = t & 63, w = t >> 6;
  if (lane == 0) redm[w] = m;
  __syncthreads();
  m = fmaxf(fmaxf(redm[0], redm[1]), fmaxf(redm[2], redm[3]));
  float s = 0.f;
#pragma unroll
  for (int i = 0; i < 16; ++i) { v[i] = __expf(v[i] - m); s += v[i]; }
#pragma unroll
  for (int off = 32; off > 0; off >>= 1) s += __shfl_xor(s, off);
  if (lane == 0) reds[w] = s;
  __syncthreads();
  s = reds[0] + reds[1] + reds[2] + reds[3];
  float inv = 1.0f / s;
#pragma unroll
  for (int i = 0; i < 8; ++i) { c0[i] = (bh)(v[i] * inv); c1[i] = (bh)(v[8 + i] * inv); }
  *(v8bf*)(p + t * 16) = c0;
  *(v8bf*)(p + t * 16 + 8) = c1;
}

extern "C" void kernel_launch(void* const* d_in, const int* in_sizes, int n_in,
                              void* d_out, int out_size, void* d_ws, size_t ws_size,
                              hipStream_t stream) {
  (void)in_sizes; (void)n_in; (void)out_size; (void)ws_size;
  const float* X  = (const float*)d_in[0];
  // d_in[1] = mask, unused by the module
  const float* Wv = (const float*)d_in[2];
  const float* bv = (const float*)d_in[3];
  const float* W1 = (const float*)d_in[4];
  const float* b1 = (const float*)d_in[5];
  const float* W2 = (const float*)d_in[6];
  const float* b2 = (const float*)d_in[7];
  float* out = (float*)d_out;

  char* ws = (char*)d_ws;
  bh* featb = (bh*)(ws);                       // 4096 x 2048 bf16 : 16 MiB
  bh* WvT   = (bh*)(ws + (16u << 20));         // 1024 x 1024      :  2 MiB
  bh* W1T   = (bh*)(ws + (18u << 20));         // 2048 x 2048      :  8 MiB
  bh* W2T   = (bh*)(ws + (26u << 20));         // 4096 x 2048      : 16 MiB
  bh* Vt    = (bh*)(ws + (42u << 20));         // 1024 x 4096      :  8 MiB
  bh* hid   = (bh*)(ws + (50u << 20));         // 4096 x 2048      : 16 MiB
  bh* scr   = (bh*)(ws + (66u << 20));         // 4096 x 4096      : 32 MiB
  float* S  = (float*)(ws + (98u << 20));      // 1024 fp32

  hipMemsetAsync(S, 0, DIM * sizeof(float), stream);
  prep_x_colsum<<<dim3(DIM / 256, 32), 256, 0, stream>>>(X, featb, S);
  prep_loo<<<dim3((TOK * DIM) / 256), 256, 0, stream>>>(X, S, featb);
  transpose_all<<<dim3(1024 + 4096 + 8192), dim3(32, 8), 0, stream>>>(
      Wv, W1, W2, WvT, W1T, W2T);

  // V^T = (feat_left @ Wv + bv)^T  -> Vt (1024 x 4096, ld 4096)
  gemm_bt<64, false, true, bh><<<dim3(DIM / 64, TOK / 128), 128, 0, stream>>>(
      featb, WvT, bv, Vt, DIM, 2 * DIM, DIM, TOK);
  // hid = relu(feat @ W1 + b1)
  gemm_bt<128, true, false, bh><<<dim3(HID / 128, TOK / 128), 128, 0, stream>>>(
      featb, W1T, b1, hid, 2 * DIM, 2 * DIM, 2 * DIM, HID);
  // scr = hid @ W2 + b2
  gemm_bt<128, false, false, bh><<<dim3(TOK / 128, TOK / 128), 128, 0, stream>>>(
      hid, W2T, b2, scr, HID, HID, HID, TOK);
  softmax_inplace<<<dim3(TOK), 256, 0, stream>>>(scr);
  // out = softmax(scr) @ V  (A = weights row-major, BT = Vt) -> fp32 d_out
  gemm_bt<64, false, false, float><<<dim3(DIM / 64, TOK / 128), 128, 0, stream>>>(
      scr, Vt, nullptr, out, TOK, TOK, TOK, DIM);
}

// Round 5
// 362.505 us; speedup vs baseline: 1.4043x; 1.1725x over previous
//
#include <hip/hip_runtime.h>
#include <hip/hip_bf16.h>

#define TOK 4096
#define DIM 1024
#define HID 2048
#define LN10K 9.210340371976184f

typedef __bf16 bh;
typedef __bf16 v8bf __attribute__((ext_vector_type(8)));
typedef float v4f __attribute__((ext_vector_type(4)));

typedef const __attribute__((address_space(1))) void* gvp;
typedef __attribute__((address_space(3))) void* svp;

__device__ __forceinline__ void gl_lds16(const bh* g, bh* s) {
  __builtin_amdgcn_global_load_lds((gvp)g, (svp)s, 16, 0, 0);
}

// ---------------- prep: cast X -> feat left half, colsum(E) ----------------
// Thread owns an (even,odd) column pair: one __sincosf serves both PE values.
// grid (DIM/512, TOK/16) = (2,256) = 512 blocks, 16 rows/thread.
__global__ __launch_bounds__(256) void prep_x_colsum(const float* __restrict__ X,
                                                     bh* __restrict__ featb,
                                                     float* __restrict__ S) {
  int cp = blockIdx.x * 256 + threadIdx.x;      // column pair 0..511
  int c = cp * 2;
  int r0 = blockIdx.y * 16;
  float inv_denom = __expf(-(float)c * (LN10K / (float)DIM));
  float s0 = 0.f, s1 = 0.f;
#pragma unroll 4
  for (int r = r0; r < r0 + 16; ++r) {
    float2 x = *(const float2*)(X + (size_t)r * DIM + c);
    float sn, cs;
    __sincosf((float)r * inv_denom, &sn, &cs);
    s0 += sn * x.x;
    s1 += cs * x.y;
    bh pair[2] = {(bh)x.x, (bh)x.y};
    *(ushort2*)(featb + (size_t)r * (2 * DIM) + c) = *(ushort2*)pair;
  }
  atomicAdd(&S[c], s0);
  atomicAdd(&S[c + 1], s1);
}

// ---------------- prep: loo -> feat right half ----------------
// 4 elements (2 pairs) per thread, float4 loads, 8B bf16 writes.
__global__ __launch_bounds__(256) void prep_loo(const float* __restrict__ X,
                                                const float* __restrict__ S,
                                                bh* __restrict__ featb) {
  size_t e4 = ((size_t)blockIdx.x * 256 + threadIdx.x) * 4;  // over TOK*DIM
  int r = (int)(e4 >> 10);
  int c = (int)(e4 & 1023);
  float4 x = *(const float4*)(X + e4);
  float4 s = *(const float4*)(S + c);
  float id0 = __expf(-(float)c * (LN10K / (float)DIM));
  float id1 = __expf(-(float)(c + 2) * (LN10K / (float)DIM));
  float sn0, cs0, sn1, cs1;
  __sincosf((float)r * id0, &sn0, &cs0);
  __sincosf((float)r * id1, &sn1, &cs1);
  const float inv = 1.0f / (float)(TOK - 1);
  bh outv[4];
  outv[0] = (bh)((s.x - sn0 * x.x) * inv);
  outv[1] = (bh)((s.y - cs0 * x.y) * inv);
  outv[2] = (bh)((s.z - sn1 * x.z) * inv);
  outv[3] = (bh)((s.w - cs1 * x.w) * inv);
  *(ushort4*)(featb + (size_t)r * (2 * DIM) + DIM + c) = *(ushort4*)outv;
}

// ---------------- fused transpose+cast of all 3 weights (1 dispatch) -------
__global__ __launch_bounds__(256) void transpose_all(const float* __restrict__ Wv,
                                                     const float* __restrict__ W1,
                                                     const float* __restrict__ W2,
                                                     bh* __restrict__ WvT,
                                                     bh* __restrict__ W1T,
                                                     bh* __restrict__ W2T) {
  __shared__ float tile[32][33];
  int bid = blockIdx.x;
  const float* in; bh* out; int Ncol, R, bx, by;
  if (bid < 1024)      { in = Wv; out = WvT; Ncol = DIM; R = DIM;
                         bx = bid & 31; by = bid >> 5; }
  else if (bid < 5120) { int b = bid - 1024; in = W1; out = W1T; Ncol = HID; R = 2 * DIM;
                         bx = b & 63; by = b >> 6; }
  else                 { int b = bid - 5120; in = W2; out = W2T; Ncol = TOK; R = HID;
                         bx = b & 127; by = b >> 7; }
  int nb = bx * 32, rb = by * 32;
  int tx = threadIdx.x, ty = threadIdx.y;  // block (32,8)
#pragma unroll
  for (int j = 0; j < 32; j += 8)
    tile[ty + j][tx] = in[(size_t)(rb + ty + j) * Ncol + nb + tx];
  __syncthreads();
#pragma unroll
  for (int j = 0; j < 32; j += 8)
    out[(size_t)(nb + ty + j) * R + rb + tx] = (bh)tile[tx][ty + j];
}

// ---------------- GEMM: C = act(A @ BT^T + bias) ----------------
// A: M x K row-major bf16 (lda). BT: N x K row-major bf16 (B^T).
// 128-thread blocks (2 waves). Block tile 128 x BN, BK=64.
// Wave tile 64 x BN. Staging: global_load_lds width=16, lane-linear LDS.
// XOR swizzle (16B grain, row&7) -> max 2-way bank aliasing (free, m136).
template <int BN, bool RELU, bool TROUT, typename OutT>
__global__ __launch_bounds__(128, 2) void gemm_bt(const bh* __restrict__ A,
                                                  const bh* __restrict__ BT,
                                                  const float* __restrict__ bias,
                                                  OutT* __restrict__ C,
                                                  int K, int lda, int ldbt, int ldc) {
  constexpr int NT = BN / 16;          // 8 (BN=128) or 4 (BN=64)
  __shared__ bh As[128 * 64];          // 16 KB
  __shared__ bh Bs[BN * 64];           // 16 or 8 KB
  const int t = threadIdx.x;
  const int bm = blockIdx.y * 128, bn = blockIdx.x * BN;

  const int sr = t >> 3, sp = t & 7;   // staging: row-in-group, chunk position
  const int c8 = (sp ^ (sr & 7)) * 8;  // logical k-offset (elems) for this thread
  const bh* gA = A + (size_t)(bm + sr) * lda + c8;
  const bh* gB = BT + (size_t)(bn + sr) * ldbt + c8;
  bh* sA = As + t * 8;
  bh* sB = Bs + t * 8;

  const int lane = t & 63, w = t >> 6;
  const int lc = lane & 15, q = lane >> 4;

  v4f acc[4][NT] = {};
  for (int k0 = 0; k0 < K; k0 += 64) {
#pragma unroll
    for (int j = 0; j < 8; ++j)
      gl_lds16(gA + k0 + j * 16 * lda, sA + j * 1024);
#pragma unroll
    for (int j = 0; j < NT; ++j)
      gl_lds16(gB + k0 + j * 16 * ldbt, sB + j * 1024);
    __syncthreads();   // drains vmcnt(0) + barrier
#pragma unroll
    for (int h = 0; h < 2; ++h) {
      const int off = ((h * 4 + q) ^ (lc & 7)) * 8;
      v8bf af[4], bfr[NT];
#pragma unroll
      for (int mt = 0; mt < 4; ++mt)
        af[mt] = *(const v8bf*)(As + (w * 64 + mt * 16 + lc) * 64 + off);
#pragma unroll
      for (int nt = 0; nt < NT; ++nt)
        bfr[nt] = *(const v8bf*)(Bs + (nt * 16 + lc) * 64 + off);
#pragma unroll
      for (int mt = 0; mt < 4; ++mt)
#pragma unroll
        for (int nt = 0; nt < NT; ++nt)
          acc[mt][nt] = __builtin_amdgcn_mfma_f32_16x16x32_bf16(af[mt], bfr[nt], acc[mt][nt], 0, 0, 0);
    }
    __syncthreads();
  }

  // C/D layout: col = lane&15, row = q*4 + r   (m89-verified)
  const int r4 = q * 4;
#pragma unroll
  for (int mt = 0; mt < 4; ++mt) {
    int row0 = bm + w * 64 + mt * 16 + r4;
#pragma unroll
    for (int nt = 0; nt < NT; ++nt) {
      int col = bn + nt * 16 + lc;
      float bb = bias ? bias[col] : 0.0f;
#pragma unroll
      for (int r = 0; r < 4; ++r) {
        float val = acc[mt][nt][r] + bb;
        if (RELU) val = fmaxf(val, 0.0f);
        if (TROUT) C[(size_t)col * ldc + (row0 + r)] = (OutT)val;
        else       C[(size_t)(row0 + r) * ldc + col] = (OutT)val;
      }
    }
  }
}

// ---------------- row softmax in place on bf16 (TOK cols) ----------------
__global__ __launch_bounds__(256) void softmax_inplace(bh* __restrict__ P) {
  int row = blockIdx.x;
  bh* p = P + (size_t)row * TOK;
  int t = threadIdx.x;
  v8bf c0 = *(v8bf*)(p + t * 16);
  v8bf c1 = *(v8bf*)(p + t * 16 + 8);
  float v[16];
#pragma unroll
  for (int i = 0; i < 8; ++i) { v[i] = (float)c0[i]; v[8 + i] = (float)c1[i]; }
  float m = v[0];
#pragma unroll
  for (int i = 1; i < 16; ++i) m = fmaxf(m, v[i]);
#pragma unroll
  for (int off = 32; off > 0; off >>= 1) m = fmaxf(m, __shfl_xor(m, off));
  __shared__ float redm[4], reds[4];
  int lane = t & 63, w = t >> 6;
  if (lane == 0) redm[w] = m;
  __syncthreads();
  m = fmaxf(fmaxf(redm[0], redm[1]), fmaxf(redm[2], redm[3]));
  float s = 0.f;
#pragma unroll
  for (int i = 0; i < 16; ++i) { v[i] = __expf(v[i] - m); s += v[i]; }
#pragma unroll
  for (int off = 32; off > 0; off >>= 1) s += __shfl_xor(s, off);
  if (lane == 0) reds[w] = s;
  __syncthreads();
  s = reds[0] + reds[1] + reds[2] + reds[3];
  float inv = 1.0f / s;
#pragma unroll
  for (int i = 0; i < 8; ++i) { c0[i] = (bh)(v[i] * inv); c1[i] = (bh)(v[8 + i] * inv); }
  *(v8bf*)(p + t * 16) = c0;
  *(v8bf*)(p + t * 16 + 8) = c1;
}

extern "C" void kernel_launch(void* const* d_in, const int* in_sizes, int n_in,
                              void* d_out, int out_size, void* d_ws, size_t ws_size,
                              hipStream_t stream) {
  (void)in_sizes; (void)n_in; (void)out_size; (void)ws_size;
  const float* X  = (const float*)d_in[0];
  // d_in[1] = mask, unused by the module
  const float* Wv = (const float*)d_in[2];
  const float* bv = (const float*)d_in[3];
  const float* W1 = (const float*)d_in[4];
  const float* b1 = (const float*)d_in[5];
  const float* W2 = (const float*)d_in[6];
  const float* b2 = (const float*)d_in[7];
  float* out = (float*)d_out;

  char* ws = (char*)d_ws;
  bh* featb = (bh*)(ws);                       // 4096 x 2048 bf16 : 16 MiB
  bh* WvT   = (bh*)(ws + (16u << 20));         // 1024 x 1024      :  2 MiB
  bh* W1T   = (bh*)(ws + (18u << 20));         // 2048 x 2048      :  8 MiB
  bh* W2T   = (bh*)(ws + (26u << 20));         // 4096 x 2048      : 16 MiB
  bh* Vt    = (bh*)(ws + (42u << 20));         // 1024 x 4096      :  8 MiB
  bh* hid   = (bh*)(ws + (50u << 20));         // 4096 x 2048      : 16 MiB
  bh* scr   = (bh*)(ws + (66u << 20));         // 4096 x 4096      : 32 MiB
  float* S  = (float*)(ws + (98u << 20));      // 1024 fp32

  hipError_t e = hipMemsetAsync(S, 0, DIM * sizeof(float), stream);
  (void)e;
  prep_x_colsum<<<dim3(DIM / 512, TOK / 16), 256, 0, stream>>>(X, featb, S);
  prep_loo<<<dim3((TOK * DIM) / 1024), 256, 0, stream>>>(X, S, featb);
  transpose_all<<<dim3(1024 + 4096 + 8192), dim3(32, 8), 0, stream>>>(
      Wv, W1, W2, WvT, W1T, W2T);

  // V^T = (feat_left @ Wv + bv)^T  -> Vt (1024 x 4096, ld 4096)
  gemm_bt<64, false, true, bh><<<dim3(DIM / 64, TOK / 128), 128, 0, stream>>>(
      featb, WvT, bv, Vt, DIM, 2 * DIM, DIM, TOK);
  // hid = relu(feat @ W1 + b1)
  gemm_bt<128, true, false, bh><<<dim3(HID / 128, TOK / 128), 128, 0, stream>>>(
      featb, W1T, b1, hid, 2 * DIM, 2 * DIM, 2 * DIM, HID);
  // scr = hid @ W2 + b2
  gemm_bt<128, false, false, bh><<<dim3(TOK / 128, TOK / 128), 128, 0, stream>>>(
      hid, W2T, b2, scr, HID, HID, HID, TOK);
  softmax_inplace<<<dim3(TOK), 256, 0, stream>>>(scr);
  // out = softmax(scr) @ V  (A = weights row-major, BT = Vt) -> fp32 d_out
  gemm_bt<64, false, false, float><<<dim3(DIM / 64, TOK / 128), 128, 0, stream>>>(
      scr, Vt, nullptr, out, TOK, TOK, TOK, DIM);
}

// Round 6
// 343.213 us; speedup vs baseline: 1.4833x; 1.0562x over previous
//
#include <hip/hip_runtime.h>
#include <hip/hip_bf16.h>

#define TOK 4096
#define DIM 1024
#define HID 2048
#define LN10K 9.210340371976184f

typedef __bf16 bh;
typedef __bf16 v8bf __attribute__((ext_vector_type(8)));
typedef float v4f __attribute__((ext_vector_type(4)));

typedef const __attribute__((address_space(1))) void* gvp;
typedef __attribute__((address_space(3))) void* svp;

__device__ __forceinline__ void gl_lds16(const bh* g, bh* s) {
  __builtin_amdgcn_global_load_lds((gvp)g, (svp)s, 16, 0, 0);
}

// ---------------- prep: cast X -> feat left half, colsum(E) ----------------
__global__ __launch_bounds__(256) void prep_x_colsum(const float* __restrict__ X,
                                                     bh* __restrict__ featb,
                                                     float* __restrict__ S) {
  int cp = blockIdx.x * 256 + threadIdx.x;      // column pair 0..511
  int c = cp * 2;
  int r0 = blockIdx.y * 16;
  float inv_denom = __expf(-(float)c * (LN10K / (float)DIM));
  float s0 = 0.f, s1 = 0.f;
#pragma unroll 4
  for (int r = r0; r < r0 + 16; ++r) {
    float2 x = *(const float2*)(X + (size_t)r * DIM + c);
    float sn, cs;
    __sincosf((float)r * inv_denom, &sn, &cs);
    s0 += sn * x.x;
    s1 += cs * x.y;
    bh pair[2] = {(bh)x.x, (bh)x.y};
    *(ushort2*)(featb + (size_t)r * (2 * DIM) + c) = *(ushort2*)pair;
  }
  atomicAdd(&S[c], s0);
  atomicAdd(&S[c + 1], s1);
}

// ---------------- prep: loo -> feat right half ----------------
__global__ __launch_bounds__(256) void prep_loo(const float* __restrict__ X,
                                                const float* __restrict__ S,
                                                bh* __restrict__ featb) {
  size_t e4 = ((size_t)blockIdx.x * 256 + threadIdx.x) * 4;  // over TOK*DIM
  int r = (int)(e4 >> 10);
  int c = (int)(e4 & 1023);
  float4 x = *(const float4*)(X + e4);
  float4 s = *(const float4*)(S + c);
  float id0 = __expf(-(float)c * (LN10K / (float)DIM));
  float id1 = __expf(-(float)(c + 2) * (LN10K / (float)DIM));
  float sn0, cs0, sn1, cs1;
  __sincosf((float)r * id0, &sn0, &cs0);
  __sincosf((float)r * id1, &sn1, &cs1);
  const float inv = 1.0f / (float)(TOK - 1);
  bh outv[4];
  outv[0] = (bh)((s.x - sn0 * x.x) * inv);
  outv[1] = (bh)((s.y - cs0 * x.y) * inv);
  outv[2] = (bh)((s.z - sn1 * x.z) * inv);
  outv[3] = (bh)((s.w - cs1 * x.w) * inv);
  *(ushort4*)(featb + (size_t)r * (2 * DIM) + DIM + c) = *(ushort4*)outv;
}

// ---------------- fused transpose+cast of all 3 weights (1 dispatch) -------
__global__ __launch_bounds__(256) void transpose_all(const float* __restrict__ Wv,
                                                     const float* __restrict__ W1,
                                                     const float* __restrict__ W2,
                                                     bh* __restrict__ WvT,
                                                     bh* __restrict__ W1T,
                                                     bh* __restrict__ W2T) {
  __shared__ float tile[32][33];
  int bid = blockIdx.x;
  const float* in; bh* out; int Ncol, R, bx, by;
  if (bid < 1024)      { in = Wv; out = WvT; Ncol = DIM; R = DIM;
                         bx = bid & 31; by = bid >> 5; }
  else if (bid < 5120) { int b = bid - 1024; in = W1; out = W1T; Ncol = HID; R = 2 * DIM;
                         bx = b & 63; by = b >> 6; }
  else                 { int b = bid - 5120; in = W2; out = W2T; Ncol = TOK; R = HID;
                         bx = b & 127; by = b >> 7; }
  int nb = bx * 32, rb = by * 32;
  int tx = threadIdx.x, ty = threadIdx.y;  // block (32,8)
#pragma unroll
  for (int j = 0; j < 32; j += 8)
    tile[ty + j][tx] = in[(size_t)(rb + ty + j) * Ncol + nb + tx];
  __syncthreads();
#pragma unroll
  for (int j = 0; j < 32; j += 8)
    out[(size_t)(nb + ty + j) * R + rb + tx] = (bh)tile[tx][ty + j];
}

// ---------------- GEMM: C = act(A @ BT^T + bias) ----------------
// 128-thread blocks (2 waves), block tile 128 x BN, BK=64, wave tile 64 x BN.
// Staging: global_load_lds width=16, lane-linear LDS, 16B-grain XOR swizzle.
template <int BN, bool RELU, bool TROUT, typename OutT>
__global__ __launch_bounds__(128, 2) void gemm_bt(const bh* __restrict__ A,
                                                  const bh* __restrict__ BT,
                                                  const float* __restrict__ bias,
                                                  OutT* __restrict__ C,
                                                  int K, int lda, int ldbt, int ldc) {
  constexpr int NT = BN / 16;          // 8 (BN=128) or 4 (BN=64)
  __shared__ bh As[128 * 64];          // 16 KB
  __shared__ bh Bs[BN * 64];           // 16 or 8 KB
  const int t = threadIdx.x;
  const int bm = blockIdx.y * 128, bn = blockIdx.x * BN;

  const int sr = t >> 3;               // staging row-in-group
  const int c8 = ((t & 7) ^ (sr & 7)) * 8;
  const bh* gA = A + (size_t)(bm + sr) * lda + c8;
  const bh* gB = BT + (size_t)(bn + sr) * ldbt + c8;
  bh* sA = As + t * 8;
  bh* sB = Bs + t * 8;

  const int lane = t & 63, w = t >> 6;
  const int lc = lane & 15, q = lane >> 4;

  v4f acc[4][NT] = {};
  for (int k0 = 0; k0 < K; k0 += 64) {
#pragma unroll
    for (int j = 0; j < 8; ++j)
      gl_lds16(gA + k0 + j * 16 * lda, sA + j * 1024);
#pragma unroll
    for (int j = 0; j < NT; ++j)
      gl_lds16(gB + k0 + j * 16 * ldbt, sB + j * 1024);
    __syncthreads();
#pragma unroll
    for (int h = 0; h < 2; ++h) {
      const int off = ((h * 4 + q) ^ (lc & 7)) * 8;
      v8bf af[4], bfr[NT];
#pragma unroll
      for (int mt = 0; mt < 4; ++mt)
        af[mt] = *(const v8bf*)(As + (w * 64 + mt * 16 + lc) * 64 + off);
#pragma unroll
      for (int nt = 0; nt < NT; ++nt)
        bfr[nt] = *(const v8bf*)(Bs + (nt * 16 + lc) * 64 + off);
#pragma unroll
      for (int mt = 0; mt < 4; ++mt)
#pragma unroll
        for (int nt = 0; nt < NT; ++nt)
          acc[mt][nt] = __builtin_amdgcn_mfma_f32_16x16x32_bf16(af[mt], bfr[nt], acc[mt][nt], 0, 0, 0);
    }
    __syncthreads();
  }

  const int r4 = q * 4;
#pragma unroll
  for (int mt = 0; mt < 4; ++mt) {
    int row0 = bm + w * 64 + mt * 16 + r4;
#pragma unroll
    for (int nt = 0; nt < NT; ++nt) {
      int col = bn + nt * 16 + lc;
      float bb = bias ? bias[col] : 0.0f;
#pragma unroll
      for (int r = 0; r < 4; ++r) {
        float val = acc[mt][nt][r] + bb;
        if (RELU) val = fmaxf(val, 0.0f);
        if (TROUT) C[(size_t)col * ldc + (row0 + r)] = (OutT)val;
        else       C[(size_t)(row0 + r) * ldc + col] = (OutT)val;
      }
    }
  }
}

// ---------------- GEMM4: out = P @ V via split-K --------------------------
// 256-thread blocks (4 waves, 2x2 of 64x64), tile 128x128, BK=64, split-K=2.
// grid (8, 32, 2) = 512 blocks -> 16 waves/CU (vs 4 for the old BN=64 config)
// to hide the L3-latency on streaming P (32 MB). kz=0 -> C0 (=d_out),
// kz=1 -> C1 (partial, reduced by add_partial).
__global__ __launch_bounds__(256, 4) void gemm4_split(const bh* __restrict__ A,
                                                      const bh* __restrict__ BT,
                                                      float* __restrict__ C0,
                                                      float* __restrict__ C1) {
  __shared__ bh As[128 * 64];          // 16 KB
  __shared__ bh Bs[128 * 64];          // 16 KB
  const int t = threadIdx.x;
  const int bm = blockIdx.y * 128, bn = blockIdx.x * 128;
  const int kbeg = blockIdx.z * (TOK / 2);

  const int sr = t >> 3;               // 0..31
  const int c8 = ((t & 7) ^ (sr & 7)) * 8;
  const bh* gA = A + (size_t)(bm + sr) * TOK + kbeg + c8;
  const bh* gB = BT + (size_t)(bn + sr) * TOK + kbeg + c8;
  bh* sA = As + t * 8;
  bh* sB = Bs + t * 8;

  const int lane = t & 63, w = t >> 6;
  const int wm = (w >> 1) * 64, wn = (w & 1) * 64;
  const int lc = lane & 15, q = lane >> 4;

  v4f acc[4][4] = {};
  for (int k0 = 0; k0 < TOK / 2; k0 += 64) {
#pragma unroll
    for (int j = 0; j < 4; ++j) {
      gl_lds16(gA + k0 + (size_t)(j * 32) * TOK, sA + j * 2048);
      gl_lds16(gB + k0 + (size_t)(j * 32) * TOK, sB + j * 2048);
    }
    __syncthreads();
#pragma unroll
    for (int h = 0; h < 2; ++h) {
      const int off = ((h * 4 + q) ^ (lc & 7)) * 8;
      v8bf af[4], bfr[4];
#pragma unroll
      for (int mt = 0; mt < 4; ++mt)
        af[mt] = *(const v8bf*)(As + (wm + mt * 16 + lc) * 64 + off);
#pragma unroll
      for (int nt = 0; nt < 4; ++nt)
        bfr[nt] = *(const v8bf*)(Bs + (wn + nt * 16 + lc) * 64 + off);
#pragma unroll
      for (int mt = 0; mt < 4; ++mt)
#pragma unroll
        for (int nt = 0; nt < 4; ++nt)
          acc[mt][nt] = __builtin_amdgcn_mfma_f32_16x16x32_bf16(af[mt], bfr[nt], acc[mt][nt], 0, 0, 0);
    }
    __syncthreads();
  }

  float* C = blockIdx.z ? C1 : C0;
  const int r4 = q * 4;
#pragma unroll
  for (int mt = 0; mt < 4; ++mt) {
    int row0 = bm + wm + mt * 16 + r4;
#pragma unroll
    for (int nt = 0; nt < 4; ++nt) {
      int col = bn + wn + nt * 16 + lc;
#pragma unroll
      for (int r = 0; r < 4; ++r)
        C[(size_t)(row0 + r) * DIM + col] = acc[mt][nt][r];
    }
  }
}

// ---------------- out += partial (float4) ----------------------------------
__global__ __launch_bounds__(256) void add_partial(float* __restrict__ out,
                                                   const float* __restrict__ part) {
  size_t i = ((size_t)blockIdx.x * 256 + threadIdx.x) * 4;
  float4 a = *(const float4*)(out + i);
  float4 b = *(const float4*)(part + i);
  a.x += b.x; a.y += b.y; a.z += b.z; a.w += b.w;
  *(float4*)(out + i) = a;
}

// ---------------- row softmax in place on bf16 (TOK cols) ----------------
__global__ __launch_bounds__(256) void softmax_inplace(bh* __restrict__ P) {
  int row = blockIdx.x;
  bh* p = P + (size_t)row * TOK;
  int t = threadIdx.x;
  v8bf c0 = *(v8bf*)(p + t * 16);
  v8bf c1 = *(v8bf*)(p + t * 16 + 8);
  float v[16];
#pragma unroll
  for (int i = 0; i < 8; ++i) { v[i] = (float)c0[i]; v[8 + i] = (float)c1[i]; }
  float m = v[0];
#pragma unroll
  for (int i = 1; i < 16; ++i) m = fmaxf(m, v[i]);
#pragma unroll
  for (int off = 32; off > 0; off >>= 1) m = fmaxf(m, __shfl_xor(m, off));
  __shared__ float redm[4], reds[4];
  int lane = t & 63, w = t >> 6;
  if (lane == 0) redm[w] = m;
  __syncthreads();
  m = fmaxf(fmaxf(redm[0], redm[1]), fmaxf(redm[2], redm[3]));
  float s = 0.f;
#pragma unroll
  for (int i = 0; i < 16; ++i) { v[i] = __expf(v[i] - m); s += v[i]; }
#pragma unroll
  for (int off = 32; off > 0; off >>= 1) s += __shfl_xor(s, off);
  if (lane == 0) reds[w] = s;
  __syncthreads();
  s = reds[0] + reds[1] + reds[2] + reds[3];
  float inv = 1.0f / s;
#pragma unroll
  for (int i = 0; i < 8; ++i) { c0[i] = (bh)(v[i] * inv); c1[i] = (bh)(v[8 + i] * inv); }
  *(v8bf*)(p + t * 16) = c0;
  *(v8bf*)(p + t * 16 + 8) = c1;
}

extern "C" void kernel_launch(void* const* d_in, const int* in_sizes, int n_in,
                              void* d_out, int out_size, void* d_ws, size_t ws_size,
                              hipStream_t stream) {
  (void)in_sizes; (void)n_in; (void)out_size; (void)ws_size;
  const float* X  = (const float*)d_in[0];
  // d_in[1] = mask, unused by the module
  const float* Wv = (const float*)d_in[2];
  const float* bv = (const float*)d_in[3];
  const float* W1 = (const float*)d_in[4];
  const float* b1 = (const float*)d_in[5];
  const float* W2 = (const float*)d_in[6];
  const float* b2 = (const float*)d_in[7];
  float* out = (float*)d_out;

  char* ws = (char*)d_ws;
  bh* featb = (bh*)(ws);                       // 4096 x 2048 bf16 : 16 MiB
  bh* WvT   = (bh*)(ws + (16u << 20));         // 1024 x 1024      :  2 MiB
  bh* W1T   = (bh*)(ws + (18u << 20));         // 2048 x 2048      :  8 MiB
  bh* W2T   = (bh*)(ws + (26u << 20));         // 4096 x 2048      : 16 MiB
  bh* Vt    = (bh*)(ws + (42u << 20));         // 1024 x 4096      :  8 MiB
  bh* hid   = (bh*)(ws + (50u << 20));         // 4096 x 2048      : 16 MiB
  bh* scr   = (bh*)(ws + (66u << 20));         // 4096 x 4096      : 32 MiB
  float* S  = (float*)(ws + (98u << 20));      // 1024 fp32
  // GEMM4 split-K partial reuses the W2T region (dead after GEMM3): 16 MiB fp32
  float* part1 = (float*)(ws + (26u << 20));

  hipError_t e = hipMemsetAsync(S, 0, DIM * sizeof(float), stream);
  (void)e;
  prep_x_colsum<<<dim3(DIM / 512, TOK / 16), 256, 0, stream>>>(X, featb, S);
  prep_loo<<<dim3((TOK * DIM) / 1024), 256, 0, stream>>>(X, S, featb);
  transpose_all<<<dim3(1024 + 4096 + 8192), dim3(32, 8), 0, stream>>>(
      Wv, W1, W2, WvT, W1T, W2T);

  // V^T = (feat_left @ Wv + bv)^T  -> Vt (1024 x 4096, ld 4096)
  gemm_bt<64, false, true, bh><<<dim3(DIM / 64, TOK / 128), 128, 0, stream>>>(
      featb, WvT, bv, Vt, DIM, 2 * DIM, DIM, TOK);
  // hid = relu(feat @ W1 + b1)
  gemm_bt<128, true, false, bh><<<dim3(HID / 128, TOK / 128), 128, 0, stream>>>(
      featb, W1T, b1, hid, 2 * DIM, 2 * DIM, 2 * DIM, HID);
  // scr = hid @ W2 + b2
  gemm_bt<128, false, false, bh><<<dim3(TOK / 128, TOK / 128), 128, 0, stream>>>(
      hid, W2T, b2, scr, HID, HID, HID, TOK);
  softmax_inplace<<<dim3(TOK), 256, 0, stream>>>(scr);
  // out = softmax(scr) @ V — split-K=2, k0 -> out, k1 -> part1, then reduce
  gemm4_split<<<dim3(DIM / 128, TOK / 128, 2), 256, 0, stream>>>(scr, Vt, out, part1);
  add_partial<<<dim3((TOK * DIM) / 1024), 256, 0, stream>>>(out, part1);
}